// Round 1
// baseline (490.375 us; speedup 1.0000x reference)
//
#include <hip/hip_runtime.h>
#include <math.h>

#define MAXK 64
#define HDIM 128
#define FDIM 64
#define KPAD 68   // 67 inputs + 1 pad to keep float4 rows

// ---------------------------------------------------------------------------
// Kernel 1: ball query. One 64-lane wave per query. batch[] is sorted, so the
// candidate set is the contiguous segment with batch == batch[key_idx[m]].
// Ordered compaction via ballot + prefix popcount reproduces "first MAX_NBRS
// valid neighbors in index order" exactly.
// ---------------------------------------------------------------------------
__global__ __launch_bounds__(64) void nbr_kernel(
    const float* __restrict__ pos, const int* __restrict__ batch,
    const int* __restrict__ key_idx, int N, int M,
    int* __restrict__ nbr, int* __restrict__ cnt_out)
{
    int m = blockIdx.x;
    if (m >= M) return;
    int lane = threadIdx.x;

    int qi = key_idx[m];
    float qx = pos[3*qi+0], qy = pos[3*qi+1], qz = pos[3*qi+2];
    int qb = batch[qi];

    // lower_bound(qb), lower_bound(qb+1) over sorted batch[]
    int lo, hi;
    { int a=0, b=N; while (a<b){ int mid=(a+b)>>1; if (batch[mid] <  qb) a=mid+1; else b=mid; } lo=a; }
    { int a=lo, b=N; while (a<b){ int mid=(a+b)>>1; if (batch[mid] <= qb) a=mid+1; else b=mid; } hi=a; }

    // NOTE: (float)0.04 != 0.2f*0.2f (1 ulp apart). Reference threshold is
    // python 0.2*0.2 -> double 0.04 -> compared as f32 => (float)0.04.
    const float R2 = 0.04f;
    // match reference formula exactly, no fma contraction:
    float q2 = __fadd_rn(__fadd_rn(__fmul_rn(qx,qx), __fmul_rn(qy,qy)), __fmul_rn(qz,qz));

    int cnt = 0;
    for (int base = lo; base < hi && cnt < MAXK; base += 64) {
        int j = base + lane;
        bool v = false;
        if (j < hi) {
            float px = pos[3*j+0], py = pos[3*j+1], pz = pos[3*j+2];
            float p2  = __fadd_rn(__fadd_rn(__fmul_rn(px,px), __fmul_rn(py,py)), __fmul_rn(pz,pz));
            float dt  = __fadd_rn(__fadd_rn(__fmul_rn(qx,px), __fmul_rn(qy,py)), __fmul_rn(qz,pz));
            float d2  = __fsub_rn(__fadd_rn(q2, p2), __fmul_rn(2.0f, dt));
            v = (d2 <= R2);
        }
        unsigned long long mask = __ballot(v);
        if (v) {
            int r = __popcll(mask & ((1ull << lane) - 1ull));
            int slot = cnt + r;
            if (slot < MAXK) nbr[m*MAXK + slot] = j;
        }
        cnt += (int)__popcll(mask);
    }
    if (cnt > MAXK) cnt = MAXK;
    if (lane == 0) cnt_out[m] = cnt;
}

// ---------------------------------------------------------------------------
// Kernel 2: per-query MLP + max-aggregate + L2 normalize.
// 256 threads = 2 groups x 128 channels. Group g owns neighbor rows
// [32g, min(32g+32, cnt)). Thread owns one output channel; W1/W2 columns live
// in registers; activation rows are LDS-broadcast float4 reads (conflict-free).
// ---------------------------------------------------------------------------
__global__ __launch_bounds__(256) void mlp_kernel(
    const float* __restrict__ x, const float* __restrict__ pos,
    const float* __restrict__ W1, const float* __restrict__ b1,
    const float* __restrict__ W2, const float* __restrict__ b2,
    const int* __restrict__ key_idx,
    const int* __restrict__ nbr, const int* __restrict__ cnt_in,
    float* __restrict__ out, int M)
{
    __shared__ __align__(16) float A[MAXK][KPAD];    // [x_j, rel, pad] 17408 B
    __shared__ __align__(16) float Hs[MAXK][HDIM];   // hidden, 32768 B
    __shared__ float pmax[2][HDIM];
    __shared__ int   nidx[MAXK];
    __shared__ float rsum[2];

    int m   = blockIdx.x;
    int tid = threadIdx.x;
    int c   = tid & 127;
    int g   = tid >> 7;

    int cnt = cnt_in[m];
    int qi  = key_idx[m];
    float qx = pos[3*qi+0], qy = pos[3*qi+1], qz = pos[3*qi+2];

    if (tid < MAXK && tid < cnt) nidx[tid] = nbr[m*MAXK + tid];
    __syncthreads();

    // ---- stage A = [x_j | pos_j - q | 0] into LDS (only rows < cnt) ----
    {
        int j = tid >> 2, part = tid & 3;           // 4 threads per row, 16 floats each
        if (j < cnt) {
            int idx = nidx[j];
            const float4* src = reinterpret_cast<const float4*>(x + (size_t)idx*FDIM + part*16);
            float4* dst = reinterpret_cast<float4*>(&A[j][part*16]);
            #pragma unroll
            for (int i = 0; i < 4; ++i) dst[i] = src[i];
        }
        if (tid < MAXK && tid < cnt) {
            int idx = nidx[tid];
            A[tid][64] = pos[3*idx+0] - qx;
            A[tid][65] = pos[3*idx+1] - qy;
            A[tid][66] = pos[3*idx+2] - qz;
            A[tid][67] = 0.f;                       // pad: avoid garbage*0 = NaN
        }
    }

    // W1 column in registers (coalesced across c)
    float w1c[KPAD];
    #pragma unroll
    for (int k = 0; k < 67; ++k) w1c[k] = W1[k*HDIM + c];
    w1c[67] = 0.f;
    float b1c = b1[c];
    __syncthreads();

    int j0 = g*32;
    int j1 = min(j0+32, cnt);

    // ---- layer 1: hidden[j][c] = relu(A[j,:] . W1[:,c] + b1[c]) ----
    for (int j = j0; j < j1; ++j) {
        const float4* Arow = reinterpret_cast<const float4*>(&A[j][0]);
        float acc = b1c;
        #pragma unroll
        for (int kk = 0; kk < 17; ++kk) {
            float4 a = Arow[kk];
            acc = fmaf(a.x, w1c[4*kk+0], acc);
            acc = fmaf(a.y, w1c[4*kk+1], acc);
            acc = fmaf(a.z, w1c[4*kk+2], acc);
            acc = fmaf(a.w, w1c[4*kk+3], acc);
        }
        Hs[j][c] = fmaxf(acc, 0.f);
    }

    // W2 column in registers
    float w2c[HDIM];
    #pragma unroll
    for (int k = 0; k < HDIM; ++k) w2c[k] = W2[k*HDIM + c];
    float b2c = b2[c];
    __syncthreads();

    // ---- layer 2 + per-group max over rows ----
    float mx = -INFINITY;
    for (int j = j0; j < j1; ++j) {
        const float4* Hrow = reinterpret_cast<const float4*>(&Hs[j][0]);
        float acc = b2c;
        #pragma unroll
        for (int kk = 0; kk < 32; ++kk) {
            float4 h4 = Hrow[kk];
            acc = fmaf(h4.x, w2c[4*kk+0], acc);
            acc = fmaf(h4.y, w2c[4*kk+1], acc);
            acc = fmaf(h4.z, w2c[4*kk+2], acc);
            acc = fmaf(h4.w, w2c[4*kk+3], acc);
        }
        mx = fmaxf(mx, acc);
    }
    pmax[g][c] = mx;
    __syncthreads();

    // ---- combine groups, L2 normalize, store ----
    float v = 0.f;
    if (g == 0) {
        v = fmaxf(pmax[0][c], pmax[1][c]);
        float s = (cnt > 0) ? v*v : 0.f;
        #pragma unroll
        for (int o = 32; o > 0; o >>= 1) s += __shfl_xor(s, o, 64);
        if ((c & 63) == 0) rsum[c >> 6] = s;
    }
    __syncthreads();
    if (g == 0) {
        float nrm = sqrtf(rsum[0] + rsum[1]);
        float o = (cnt > 0) ? v / fmaxf(nrm, 1e-12f) : 0.f;
        out[(size_t)m*HDIM + c] = o;
    }
}

extern "C" void kernel_launch(void* const* d_in, const int* in_sizes, int n_in,
                              void* d_out, int out_size, void* d_ws, size_t ws_size,
                              hipStream_t stream)
{
    const float* x       = (const float*)d_in[0];
    const float* pos     = (const float*)d_in[1];
    const float* W1      = (const float*)d_in[2];
    const float* b1      = (const float*)d_in[3];
    const float* W2      = (const float*)d_in[4];
    const float* b2      = (const float*)d_in[5];
    const int*   batch   = (const int*)d_in[6];
    const int*   key_idx = (const int*)d_in[7];

    int N = in_sizes[6];   // 100000
    int M = in_sizes[7];   // 2048

    int* nbr = (int*)d_ws;                   // [M*64]
    int* cnt = nbr + (size_t)M * MAXK;       // [M]

    nbr_kernel<<<M, 64, 0, stream>>>(pos, batch, key_idx, N, M, nbr, cnt);
    mlp_kernel<<<M, 256, 0, stream>>>(x, pos, W1, b1, W2, b2, key_idx, nbr, cnt,
                                      (float*)d_out, M);
}

// Round 2
// 260.192 us; speedup vs baseline: 1.8847x; 1.8847x over previous
//
#include <hip/hip_runtime.h>
#include <math.h>

#define MAXK 64
#define HDIM 128
#define FDIM 64
#define KPAD 68   // 67 inputs + 1 pad to keep float4 rows

// ---------------------------------------------------------------------------
// Kernel 1: ball query. One 256-thread block (4 waves) per query. batch[] is
// sorted, so candidates are a contiguous segment. Each iteration tests 256
// candidates; ordered compaction across the 4 waves via LDS ballot-mask
// exchange reproduces "first MAX_NBRS valid in index order" exactly.
// ---------------------------------------------------------------------------
__global__ __launch_bounds__(256) void nbr_kernel(
    const float* __restrict__ pos, const int* __restrict__ batch,
    const int* __restrict__ key_idx, int N, int M,
    int* __restrict__ nbr, int* __restrict__ cnt_out)
{
    __shared__ unsigned long long smask[4];
    __shared__ int s_seg[2];

    int m = blockIdx.x;
    int tid  = threadIdx.x;
    int lane = tid & 63;
    int w    = tid >> 6;

    int qi = key_idx[m];
    float qx = pos[3*qi+0], qy = pos[3*qi+1], qz = pos[3*qi+2];
    int qb = batch[qi];

    if (tid == 0) {
        int a = 0, b = N;
        while (a < b) { int mid = (a+b) >> 1; if (batch[mid] <  qb) a = mid+1; else b = mid; }
        s_seg[0] = a;
        int a2 = a, b2 = N;
        while (a2 < b2) { int mid = (a2+b2) >> 1; if (batch[mid] <= qb) a2 = mid+1; else b2 = mid; }
        s_seg[1] = a2;
    }
    __syncthreads();
    int lo = s_seg[0], hi = s_seg[1];

    // NOTE: (float)0.04 != 0.2f*0.2f (1 ulp apart). Reference threshold is
    // python 0.04 -> f32. Match reference d2 formula exactly (no fma fusion).
    const float R2 = 0.04f;
    float q2 = __fadd_rn(__fadd_rn(__fmul_rn(qx,qx), __fmul_rn(qy,qy)), __fmul_rn(qz,qz));

    int cnt = 0;
    for (int base = lo; base < hi && cnt < MAXK; base += 256) {
        int j = base + tid;
        bool v = false;
        if (j < hi) {
            float px = pos[3*j+0], py = pos[3*j+1], pz = pos[3*j+2];
            float p2 = __fadd_rn(__fadd_rn(__fmul_rn(px,px), __fmul_rn(py,py)), __fmul_rn(pz,pz));
            float dt = __fadd_rn(__fadd_rn(__fmul_rn(qx,px), __fmul_rn(qy,py)), __fmul_rn(qz,pz));
            float d2 = __fsub_rn(__fadd_rn(q2, p2), __fmul_rn(2.0f, dt));
            v = (d2 <= R2);
        }
        unsigned long long mask = __ballot(v);
        if (lane == 0) smask[w] = mask;
        __syncthreads();
        unsigned long long m0 = smask[0], m1 = smask[1], m2 = smask[2], m3 = smask[3];
        int pre = 0;
        if (w > 0) pre += (int)__popcll(m0);
        if (w > 1) pre += (int)__popcll(m1);
        if (w > 2) pre += (int)__popcll(m2);
        int total = (int)(__popcll(m0) + __popcll(m1) + __popcll(m2) + __popcll(m3));
        if (v) {
            int slot = cnt + pre + (int)__popcll(mask & ((1ull << lane) - 1ull));
            if (slot < MAXK) nbr[m*MAXK + slot] = j;
        }
        cnt += total;
        __syncthreads();   // protect smask before next iteration overwrites
    }
    if (cnt > MAXK) cnt = MAXK;
    if (tid == 0) cnt_out[m] = cnt;
}

// ---------------------------------------------------------------------------
// Kernel 2: per-query MLP + max-aggregate + L2 normalize.
// 256 threads = 2 groups x 128 channels. Rows INTERLEAVED between groups
// (group g owns rows g, g+2, ...) so both groups stay busy for any cnt.
// 4 rows in flight per thread (4 independent accumulators) to break the
// fma dependency chain (round-1 VALUBusy was 14.5% == serial-chain bound).
// ---------------------------------------------------------------------------
__global__ __launch_bounds__(256) void mlp_kernel(
    const float* __restrict__ x, const float* __restrict__ pos,
    const float* __restrict__ W1, const float* __restrict__ b1,
    const float* __restrict__ W2, const float* __restrict__ b2,
    const int* __restrict__ key_idx,
    const int* __restrict__ nbr, const int* __restrict__ cnt_in,
    float* __restrict__ out, int M)
{
    __shared__ __align__(16) float A[MAXK][KPAD];    // [x_j, rel, pad]
    __shared__ __align__(16) float Hs[MAXK][HDIM];   // hidden
    __shared__ float pmax[2][HDIM];
    __shared__ int   nidx[MAXK];
    __shared__ float rsum[2];

    int m   = blockIdx.x;
    int tid = threadIdx.x;
    int c   = tid & 127;
    int g   = tid >> 7;

    int cnt = cnt_in[m];
    int qi  = key_idx[m];
    float qx = pos[3*qi+0], qy = pos[3*qi+1], qz = pos[3*qi+2];

    if (tid < MAXK && tid < cnt) nidx[tid] = nbr[m*MAXK + tid];
    __syncthreads();

    // ---- stage A = [x_j | pos_j - q | 0] into LDS (only rows < cnt) ----
    {
        int j = tid >> 2, part = tid & 3;           // 4 threads per row
        if (j < cnt) {
            int idx = nidx[j];
            const float4* src = reinterpret_cast<const float4*>(x + (size_t)idx*FDIM + part*16);
            float4* dst = reinterpret_cast<float4*>(&A[j][part*16]);
            #pragma unroll
            for (int i = 0; i < 4; ++i) dst[i] = src[i];
        }
        if (tid < MAXK && tid < cnt) {
            int idx = nidx[tid];
            A[tid][64] = pos[3*idx+0] - qx;
            A[tid][65] = pos[3*idx+1] - qy;
            A[tid][66] = pos[3*idx+2] - qz;
            A[tid][67] = 0.f;
        }
    }

    // W1 column in registers (coalesced across c)
    float w1c[KPAD];
    #pragma unroll
    for (int k = 0; k < 67; ++k) w1c[k] = W1[k*HDIM + c];
    w1c[67] = 0.f;
    float b1c = b1[c];
    __syncthreads();

    // ---- layer 1: 4 interleaved rows in flight ----
    for (int r0 = g; r0 < cnt; r0 += 8) {
        int ra = r0, rb = r0 + 2, rc = r0 + 4, rd = r0 + 6;
        int sb = (rb < cnt) ? rb : ra;
        int sc = (rc < cnt) ? rc : ra;
        int sd = (rd < cnt) ? rd : ra;
        const float4* Aa = reinterpret_cast<const float4*>(&A[ra][0]);
        const float4* Ab = reinterpret_cast<const float4*>(&A[sb][0]);
        const float4* Ac = reinterpret_cast<const float4*>(&A[sc][0]);
        const float4* Ad = reinterpret_cast<const float4*>(&A[sd][0]);
        float aa = b1c, ab = b1c, ac = b1c, ad = b1c;
        #pragma unroll
        for (int kk = 0; kk < 17; ++kk) {
            float4 va = Aa[kk], vb = Ab[kk], vc = Ac[kk], vd = Ad[kk];
            float w0 = w1c[4*kk+0], w1v = w1c[4*kk+1], w2v = w1c[4*kk+2], w3 = w1c[4*kk+3];
            aa = fmaf(va.x, w0, aa); ab = fmaf(vb.x, w0, ab); ac = fmaf(vc.x, w0, ac); ad = fmaf(vd.x, w0, ad);
            aa = fmaf(va.y, w1v, aa); ab = fmaf(vb.y, w1v, ab); ac = fmaf(vc.y, w1v, ac); ad = fmaf(vd.y, w1v, ad);
            aa = fmaf(va.z, w2v, aa); ab = fmaf(vb.z, w2v, ab); ac = fmaf(vc.z, w2v, ac); ad = fmaf(vd.z, w2v, ad);
            aa = fmaf(va.w, w3, aa); ab = fmaf(vb.w, w3, ab); ac = fmaf(vc.w, w3, ac); ad = fmaf(vd.w, w3, ad);
        }
        Hs[ra][c] = fmaxf(aa, 0.f);
        if (rb < cnt) Hs[rb][c] = fmaxf(ab, 0.f);
        if (rc < cnt) Hs[rc][c] = fmaxf(ac, 0.f);
        if (rd < cnt) Hs[rd][c] = fmaxf(ad, 0.f);
    }

    // W2 column in registers
    float w2c[HDIM];
    #pragma unroll
    for (int k = 0; k < HDIM; ++k) w2c[k] = W2[k*HDIM + c];
    float b2c = b2[c];
    __syncthreads();

    // ---- layer 2 + max over rows, 4 rows in flight ----
    float mx = -INFINITY;
    for (int r0 = g; r0 < cnt; r0 += 8) {
        int ra = r0, rb = r0 + 2, rc = r0 + 4, rd = r0 + 6;
        int sb = (rb < cnt) ? rb : ra;
        int sc = (rc < cnt) ? rc : ra;
        int sd = (rd < cnt) ? rd : ra;
        const float4* Ha = reinterpret_cast<const float4*>(&Hs[ra][0]);
        const float4* Hb = reinterpret_cast<const float4*>(&Hs[sb][0]);
        const float4* Hc = reinterpret_cast<const float4*>(&Hs[sc][0]);
        const float4* Hd = reinterpret_cast<const float4*>(&Hs[sd][0]);
        float aa = b2c, ab = b2c, ac = b2c, ad = b2c;
        #pragma unroll
        for (int kk = 0; kk < 32; ++kk) {
            float4 va = Ha[kk], vb = Hb[kk], vc = Hc[kk], vd = Hd[kk];
            float w0 = w2c[4*kk+0], w1v = w2c[4*kk+1], w2v = w2c[4*kk+2], w3 = w2c[4*kk+3];
            aa = fmaf(va.x, w0, aa); ab = fmaf(vb.x, w0, ab); ac = fmaf(vc.x, w0, ac); ad = fmaf(vd.x, w0, ad);
            aa = fmaf(va.y, w1v, aa); ab = fmaf(vb.y, w1v, ab); ac = fmaf(vc.y, w1v, ac); ad = fmaf(vd.y, w1v, ad);
            aa = fmaf(va.z, w2v, aa); ab = fmaf(vb.z, w2v, ab); ac = fmaf(vc.z, w2v, ac); ad = fmaf(vd.z, w2v, ad);
            aa = fmaf(va.w, w3, aa); ab = fmaf(vb.w, w3, ab); ac = fmaf(vc.w, w3, ac); ad = fmaf(vd.w, w3, ad);
        }
        mx = fmaxf(mx, aa);
        if (rb < cnt) mx = fmaxf(mx, ab);
        if (rc < cnt) mx = fmaxf(mx, ac);
        if (rd < cnt) mx = fmaxf(mx, ad);
    }
    pmax[g][c] = mx;
    __syncthreads();

    // ---- combine groups, L2 normalize, store ----
    float v = 0.f;
    if (g == 0) {
        v = fmaxf(pmax[0][c], pmax[1][c]);
        float s = (cnt > 0) ? v*v : 0.f;
        #pragma unroll
        for (int o = 32; o > 0; o >>= 1) s += __shfl_xor(s, o, 64);
        if ((c & 63) == 0) rsum[c >> 6] = s;
    }
    __syncthreads();
    if (g == 0) {
        float nrm = sqrtf(rsum[0] + rsum[1]);
        float o = (cnt > 0) ? v / fmaxf(nrm, 1e-12f) : 0.f;
        out[(size_t)m*HDIM + c] = o;
    }
}

extern "C" void kernel_launch(void* const* d_in, const int* in_sizes, int n_in,
                              void* d_out, int out_size, void* d_ws, size_t ws_size,
                              hipStream_t stream)
{
    const float* x       = (const float*)d_in[0];
    const float* pos     = (const float*)d_in[1];
    const float* W1      = (const float*)d_in[2];
    const float* b1      = (const float*)d_in[3];
    const float* W2      = (const float*)d_in[4];
    const float* b2      = (const float*)d_in[5];
    const int*   batch   = (const int*)d_in[6];
    const int*   key_idx = (const int*)d_in[7];

    int N = in_sizes[6];   // 100000
    int M = in_sizes[7];   // 2048

    int* nbr = (int*)d_ws;                   // [M*64]
    int* cnt = nbr + (size_t)M * MAXK;       // [M]

    nbr_kernel<<<M, 256, 0, stream>>>(pos, batch, key_idx, N, M, nbr, cnt);
    mlp_kernel<<<M, 256, 0, stream>>>(x, pos, W1, b1, W2, b2, key_idx, nbr, cnt,
                                      (float*)d_out, M);
}